// Round 11
// baseline (89.280 us; speedup 1.0000x reference)
//
#include <hip/hip_runtime.h>
#include <math.h>

// LocalContrastNormalization: out = sigmoid(0.5*(x-mu)/(sigma+eps)),
// mu/sigma from 31x31 zero-padded box filter (separable).
// v11 = v10 (producer/consumer waves, double-buffered transposed LDS,
// lgkm-only barriers, 1 barrier/phase) with a PREFIX-SCAN CONSUMER:
//   16 own-col reads -> lane-local prefix -> 6-step shfl_up wave scan ->
//   PX written back IN PLACE (+ right-pad = TOTAL; left pads stay 0) ->
//   each output j is the independent difference PX[c+15]-PX[c-16]
//   (2 compile-time-offset b64 reads). Removes the 31-add warm-up chain
//   and the 16-step serial slide chain entirely -> full ILP into the
//   4-transcendental pointwise tail.

#define KSZ    31
#define PAD    15
#define IMG_H  1024
#define IMG_W  1024
#define SH     64                // rows per block
#define GP     4                 // rows per group/phase
#define NPH    (SH / GP)         // 16 phases
#define NT     512
#define LROW   66                // transposed stride in float2 units
#define LBUF   (16 * LROW)       // 1056 float2 per row-slot
#define EPSV   1e-5f

#define LDS_BARRIER() do {                                   \
    asm volatile("s_waitcnt lgkmcnt(0)" ::: "memory");       \
    __builtin_amdgcn_s_barrier();                            \
} while (0)

__global__ __launch_bounds__(NT, 4)
void lcn_fused_kernel(const float* __restrict__ x, float* __restrict__ out) {
    // XCD-aware bijective swizzle (gridDim.x = 512, %8==0).
    const int cpx = gridDim.x >> 3;
    const int bid = (blockIdx.x & 7) * cpx + (blockIdx.x >> 3);

    const int chunk = bid & 15;            // 16 chunks of 64 rows per image
    const int b     = bid >> 4;
    const int y0    = chunk * SH;

    const float* img  = x   + (size_t)b * (IMG_H * IMG_W);
    float*       oimg = out + (size_t)b * (IMG_H * IMG_W);

    __shared__ float2 vbuf[2][GP][LBUF];   // double-buffered, transposed

    const int t    = threadIdx.x;
    const int wave = t >> 6;               // 0..7
    const int lane = t & 63;

    // Pad init: left pads (iv<16 -> k*LROW) must be 0 (= prefix before col 0).
    // Right pads are rewritten with TOTAL by consumers every phase.
    if (t < 256) {
        const int s = t >> 5;              // slot 0..7
        const int k = t & 31;
        float2* vb = &vbuf[s >> 2][s & 3][0];
        if (k < 16) vb[k * LROW] = make_float2(0.f, 0.f);
        else        vb[(k - 16) * LROW + (LROW - 1)] = make_float2(0.f, 0.f);
    }

    const float inv = 1.0f / 961.0f;

    if (wave >= 4) {
        // ================= PRODUCER (waves 4..7) =================
        const int pt = t & 255;            // 0..255
        const int c0 = 4 * pt;             // 4 consecutive cols

        const int iv  = c0 + 16;
        const int wp0 = ((iv    ) & 15) * LROW + ((iv    ) >> 4);
        const int wp1 = ((iv + 1) & 15) * LROW + ((iv + 1) >> 4);
        const int wp2 = ((iv + 2) & 15) * LROW + ((iv + 2) >> 4);
        const int wp3 = ((iv + 3) & 15) * LROW + ((iv + 3) >> 4);

        // Warm-up: W(y0) over rows [y0-15, y0+15] (top never clips).
        float vs0=0,vs1=0,vs2=0,vs3=0, vq0=0,vq1=0,vq2=0,vq3=0;
        for (int y = y0 - PAD; y <= y0 + PAD; ++y) {
            const int yc = max(y, 0);
            float4 v = *(const float4*)(img + (size_t)yc * IMG_W + c0);
            const float m = (y >= 0) ? 1.f : 0.f;
            v.x *= m; v.y *= m; v.z *= m; v.w *= m;
            vs0 += v.x; vq0 = fmaf(v.x, v.x, vq0);
            vs1 += v.y; vq1 = fmaf(v.y, v.y, vq1);
            vs2 += v.z; vq2 = fmaf(v.z, v.z, vq2);
            vs3 += v.w; vq3 = fmaf(v.w, v.w, vq3);
        }

        // Prologue: publish G0 (rows y0..y0+3) into buf0, sliding directly.
        #pragma unroll
        for (int r = 0; r < GP; ++r) {
            vbuf[0][r][wp0] = make_float2(vs0, vq0);
            vbuf[0][r][wp1] = make_float2(vs1, vq1);
            vbuf[0][r][wp2] = make_float2(vs2, vq2);
            vbuf[0][r][wp3] = make_float2(vs3, vq3);
            const int ys  = y0 + r - PAD;
            const int ya  = y0 + r + PAD + 1;      // <= y0+19: never clips
            const int ysc = max(ys, 0);
            float4 vS = *(const float4*)(img + (size_t)ysc * IMG_W + c0);
            float4 vA = *(const float4*)(img + (size_t)ya  * IMG_W + c0);
            const float mS = (ys >= 0) ? 1.f : 0.f;
            float s0 = vS.x*mS, s1 = vS.y*mS, s2 = vS.z*mS, s3 = vS.w*mS;
            vs0 += vA.x - s0; vq0 = fmaf(vA.x, vA.x, vq0); vq0 = fmaf(-s0, s0, vq0);
            vs1 += vA.y - s1; vq1 = fmaf(vA.y, vA.y, vq1); vq1 = fmaf(-s1, s1, vq1);
            vs2 += vA.z - s2; vq2 = fmaf(vA.z, vA.z, vq2); vq2 = fmaf(-s2, s2, vq2);
            vs3 += vA.w - s3; vq3 = fmaf(vA.w, vA.w, vq3); vq3 = fmaf(-s3, s3, vq3);
        }

        // Prefetch slide rows for phase 0 (publish base y0+GP).
        float4 pfS[GP], pfA[GP];
        {
            const int base = y0 + GP;
            #pragma unroll
            for (int r = 0; r < GP; ++r) {
                const int ys = base + r - PAD;
                const int ya = base + r + PAD + 1;
                pfS[r] = *(const float4*)(img + (size_t)max(ys, 0) * IMG_W + c0);
                pfA[r] = *(const float4*)(img + (size_t)min(ya, IMG_H - 1) * IMG_W + c0);
            }
        }

        for (int p = 0; p < NPH; ++p) {
            LDS_BARRIER();
            if (p < NPH - 1) {
                const int base = y0 + GP * (p + 1);
                float2* dst = &vbuf[(p + 1) & 1][0][0];
                #pragma unroll
                for (int r = 0; r < GP; ++r) {
                    float2* d = dst + r * LBUF;
                    d[wp0] = make_float2(vs0, vq0);
                    d[wp1] = make_float2(vs1, vq1);
                    d[wp2] = make_float2(vs2, vq2);
                    d[wp3] = make_float2(vs3, vq3);
                    const int ys = base + r - PAD;
                    const int ya = base + r + PAD + 1;
                    const float mS = (ys >= 0)    ? 1.f : 0.f;
                    const float mA = (ya < IMG_H) ? 1.f : 0.f;
                    float s0 = pfS[r].x*mS, s1 = pfS[r].y*mS,
                          s2 = pfS[r].z*mS, s3 = pfS[r].w*mS;
                    float a0 = pfA[r].x*mA, a1 = pfA[r].y*mA,
                          a2 = pfA[r].z*mA, a3 = pfA[r].w*mA;
                    vs0 += a0 - s0; vq0 = fmaf(a0, a0, vq0); vq0 = fmaf(-s0, s0, vq0);
                    vs1 += a1 - s1; vq1 = fmaf(a1, a1, vq1); vq1 = fmaf(-s1, s1, vq1);
                    vs2 += a2 - s2; vq2 = fmaf(a2, a2, vq2); vq2 = fmaf(-s2, s2, vq2);
                    vs3 += a3 - s3; vq3 = fmaf(a3, a3, vq3); vq3 = fmaf(-s3, s3, vq3);
                }
                if (p < NPH - 2) {        // prefetch for next phase's publish
                    const int base2 = y0 + GP * (p + 2);
                    #pragma unroll
                    for (int r = 0; r < GP; ++r) {
                        const int ys = base2 + r - PAD;
                        const int ya = base2 + r + PAD + 1;
                        pfS[r] = *(const float4*)(img + (size_t)max(ys, 0) * IMG_W + c0);
                        pfA[r] = *(const float4*)(img + (size_t)min(ya, IMG_H - 1) * IMG_W + c0);
                    }
                }
            }
        }
    } else {
        // ================= CONSUMER (waves 0..3) =================
        // Lane owns cols [16*lane, 16*lane+16). Transposed slot:
        //   own col j     -> phys (rel. +lane) j*66 + 1
        //   PX[c-16]      -> phys j*66 + 0      (lane-1's PX[j]; lane0 -> pad 0)
        //   PX[c+15], j>0 -> phys (j-1)*66 + 2  (lane+1's PX[j-1]; lane63 -> TOTAL pad)
        //   PX[c+15], j=0 -> phys 15*66 + 1     (own PX[15])
        const int cbase = lane << 4;

        for (int p = 0; p < NPH; ++p) {
            LDS_BARRIER();
            const int row = y0 + GP * p + wave;

            // x-row issued first; latency hidden under scan + LDS work.
            const float* xr = img + (size_t)row * IMG_W + cbase;
            float4 xa = ((const float4*)xr)[0];
            float4 xb = ((const float4*)xr)[1];
            float4 xc = ((const float4*)xr)[2];
            float4 xd = ((const float4*)xr)[3];

            float2* slot = &vbuf[p & 1][wave][0];
            float2* vr   = slot + lane;

            // ---- read own 16 vertical (sum,sumsq) values ----
            float2 v[16];
            #pragma unroll
            for (int j = 0; j < 16; ++j) v[j] = vr[j * LROW + 1];

            // ---- lane-local inclusive prefix ----
            #pragma unroll
            for (int j = 1; j < 16; ++j) { v[j].x += v[j-1].x; v[j].y += v[j-1].y; }

            // ---- wave-level inclusive scan of lane totals ----
            float Ts = v[15].x, Tq = v[15].y;
            #pragma unroll
            for (int d = 1; d < 64; d <<= 1) {
                float us = __shfl_up(Ts, d);
                float uq = __shfl_up(Tq, d);
                if (lane >= d) { Ts += us; Tq += uq; }
            }
            const float Bs = Ts - v[15].x;     // exclusive base for this lane
            const float Bq = Tq - v[15].y;

            // ---- publish PX in place (+ right-pad = TOTAL) ----
            #pragma unroll
            for (int j = 0; j < 16; ++j)
                vr[j * LROW + 1] = make_float2(Bs + v[j].x, Bq + v[j].y);
            const float TOTs = __shfl(Ts, 63);
            const float TOTq = __shfl(Tq, 63);
            if (lane < 16) slot[lane * LROW + (LROW - 1)] = make_float2(TOTs, TOTq);
            // Cross-lane visibility of PX before window reads.
            asm volatile("s_waitcnt lgkmcnt(0)" ::: "memory");
            __builtin_amdgcn_sched_barrier(0);

            // ---- independent window differences + pointwise ----
            float xs[16] = { xa.x, xa.y, xa.z, xa.w,  xb.x, xb.y, xb.z, xb.w,
                             xc.x, xc.y, xc.z, xc.w,  xd.x, xd.y, xd.z, xd.w };
            float res[16];
            #pragma unroll
            for (int j = 0; j < 16; ++j) {
                float2 hi = (j == 0) ? vr[15 * LROW + 1] : vr[(j - 1) * LROW + 2];
                float2 lo = vr[j * LROW];
                const float hs = hi.x - lo.x;
                const float hq = hi.y - lo.y;
                const float mean = hs * inv;
                const float var  = fmaf(-mean, mean, hq * inv);
                const float stdv = sqrtf(fmaxf(var, EPSV));
                const float norm = (xs[j] - mean) *
                                   __builtin_amdgcn_rcpf(stdv + EPSV);
                res[j] = __builtin_amdgcn_rcpf(1.0f + __expf(-0.5f * norm));
            }

            // Proven exact-131MB epilogue: 4 back-to-back float4 stores.
            float* orow = oimg + (size_t)row * IMG_W + cbase;
            ((float4*)orow)[0] = make_float4(res[0],  res[1],  res[2],  res[3]);
            ((float4*)orow)[1] = make_float4(res[4],  res[5],  res[6],  res[7]);
            ((float4*)orow)[2] = make_float4(res[8],  res[9],  res[10], res[11]);
            ((float4*)orow)[3] = make_float4(res[12], res[13], res[14], res[15]);
        }
    }
}

extern "C" void kernel_launch(void* const* d_in, const int* in_sizes, int n_in,
                              void* d_out, int out_size, void* d_ws, size_t ws_size,
                              hipStream_t stream) {
    (void)n_in; (void)out_size; (void)d_ws; (void)ws_size;
    const float* x = (const float*)d_in[0];
    float* out = (float*)d_out;
    const int B = in_sizes[0] / (IMG_H * IMG_W);   // 32
    dim3 grid(B * (IMG_H / SH));                   // 512 blocks
    lcn_fused_kernel<<<grid, NT, 0, stream>>>(x, out);
}